// Round 1
// 2152.421 us; speedup vs baseline: 1.0936x; 1.0936x over previous
//
#include <hip/hip_runtime.h>
#include <hip/hip_bf16.h>
#include <stdint.h>

// Leaky RNN: v_t = 0.9 v_{t-1} + 0.1 (W_hid fr_{t-1} + b_hid + u_t), fr = relu(v)
// Phase A: u_proj (fp32 tiled GEMM) written into d_out in place.
// Phase B: persistent 128-wave scan, SWAPPED MFMA operands:
//   out'[n][m] = sum_k W[n][k] fr[m][k]  (A = W in registers, B = fr from exchange)
//   D layout: lane holds out'[4 consecutive hid rows][one batch col]  ==> after
//   pack4 each lane's 8B packet IS one B-fragment sub-packet of the next step.
//   So publish = pack4 + tag + one relaxed agent-scope 8B atomic store; consume
//   = two 8B atomic loads per k-tile. NO LDS, NO __syncthreads in the scan.
//   SELF-VALIDATING: fr>=0 so bf16 sign bits are free -- producers OR a
//   step-parity tag into all sign bits and store fire-and-forget; consumers
//   poll their own fragment loads until every packet carries the expected tag
//   (no flags, no vmcnt(0) ack, no fences). ABA over the 4-step tag period is
//   excluded by per-location coherence: the consumer observed the opposite-tag
//   value at these same addresses 2 steps ago.

#define SEQ   1024
#define BATCH 64
#define INDIM 128
#define HID   512
#define HG    16   // hid groups (k-chunks of 32)
#define BGN   4    // batch groups of 16

typedef __attribute__((ext_vector_type(8))) short   short8;
typedef __attribute__((ext_vector_type(4))) float   floatx4;
typedef unsigned long long ull;

__device__ __forceinline__ unsigned short f2bf(float x) {
  union { float f; unsigned int u; } v; v.f = x;
  unsigned int r = v.u + 0x7fffu + ((v.u >> 16) & 1u);  // RNE
  return (unsigned short)(r >> 16);
}
__device__ __forceinline__ ull pack4(unsigned short a, unsigned short b,
                                     unsigned short c, unsigned short d) {
  return (ull)a | ((ull)b << 16) | ((ull)c << 32) | ((ull)d << 48);
}

// ---------------- Phase A: u_proj = input @ W_in^T + b_in  (fp32) -----------
#define TA_SB 64
#define TA_H  128
#define TA_K  64
#define APAD  65

__global__ __launch_bounds__(256) void uproj_kernel(
    const float* __restrict__ inp, const float* __restrict__ Win,
    const float* __restrict__ bin, float* __restrict__ out)
{
  __shared__ float sIn[TA_SB * APAD];
  __shared__ float sW [TA_H  * APAD];
  const int tid = threadIdx.x;
  const int sb0 = (blockIdx.x >> 2) * TA_SB;
  const int h0  = (blockIdx.x & 3) * TA_H;
  const int tx = tid & 15, ty = tid >> 4;

  float acc[4][8];
  #pragma unroll
  for (int i = 0; i < 4; ++i)
    #pragma unroll
    for (int j = 0; j < 8; ++j) acc[i][j] = 0.f;

  for (int kt = 0; kt < INDIM / TA_K; ++kt) {
    #pragma unroll
    for (int p = 0; p < 4; ++p) {
      int idx = tid + 256 * p;
      int row = idx >> 4, c4 = (idx & 15) << 2;
      const float4 v = *(const float4*)(inp + (size_t)(sb0 + row) * INDIM + kt * TA_K + c4);
      float* d = sIn + row * APAD + c4;
      d[0] = v.x; d[1] = v.y; d[2] = v.z; d[3] = v.w;
    }
    #pragma unroll
    for (int p = 0; p < 8; ++p) {
      int idx = tid + 256 * p;
      int row = idx >> 4, c4 = (idx & 15) << 2;
      const float4 v = *(const float4*)(Win + (size_t)(h0 + row) * INDIM + kt * TA_K + c4);
      float* d = sW + row * APAD + c4;
      d[0] = v.x; d[1] = v.y; d[2] = v.z; d[3] = v.w;
    }
    __syncthreads();

    for (int k = 0; k < TA_K; ++k) {
      float a[4], b[8];
      #pragma unroll
      for (int i = 0; i < 4; ++i) a[i] = sIn[(ty + 16 * i) * APAD + k];
      #pragma unroll
      for (int j = 0; j < 8; ++j) b[j] = sW[(tx + 16 * j) * APAD + k];
      #pragma unroll
      for (int i = 0; i < 4; ++i)
        #pragma unroll
        for (int j = 0; j < 8; ++j) acc[i][j] = fmaf(a[i], b[j], acc[i][j]);
    }
    __syncthreads();
  }

  #pragma unroll
  for (int j = 0; j < 8; ++j) {
    float bb = bin[h0 + tx + 16 * j];
    #pragma unroll
    for (int i = 0; i < 4; ++i)
      out[(size_t)(sb0 + ty + 16 * i) * HID + h0 + tx + 16 * j] = acc[i][j] + bb;
  }
}

// ---------------- Phase B: persistent sequential scan -----------------------
// 128 single-wave WGs: bg = bid>>5 (4 batch groups of 16), hg = (bid>>1)&15
// (k-tile of 32 hid rows), w = bid&1 (16-row half of the k-tile).
// frA layout (ull units): [slot=2][bg=4][kk=16][q''=8][m=16] = 128 KB, where
// q'' indexes 4-row hid blocks within a 32-row k-tile and m the batch col.
// Producer lane (q=lane>>4, m=lane&15) of half w owns q''=4w+q.
// Consumer lane (q,m) of tile kk loads q''=2q (lo) and 2q+1 (hi):
//   exactly B[k=8q+j][m], j=0..7 -- a ready-made MFMA B fragment.
__global__ __launch_bounds__(64) void scan_kernel(
    const float* __restrict__ Whid, const float* __restrict__ bhid,
    float* __restrict__ uo,      // d_out: u_proj in, fr out (in place)
    ull* __restrict__ frA)
{
  const int lane = threadIdx.x & 63;
  const int bid  = blockIdx.x;
  const int bg = bid >> 5;
  const int hg = (bid >> 1) & 15;
  const int w  = bid & 1;
  const int b0 = bg * 16;
  const int m  = lane & 15;          // batch col within group (D col)
  const int q  = lane >> 4;
  const int n0 = hg * 32 + w * 16 + q * 4;   // this lane's 4 hid rows (D rows)
  const int na = hg * 32 + w * 16 + m;       // A-fragment hid row

  // ---- one-time: W_hid A-fragments straight into registers (bf16) ---------
  // aw[kk] lane layout: A[n=lane&15 (local)][k=(lane>>4)*8+j], global row na.
  short8 aw[HG];
  {
    const float* wrow = Whid + (size_t)na * HID + q * 8;
    #pragma unroll
    for (int kk = 0; kk < HG; ++kk) {
      const float4 a = *(const float4*)(wrow + kk * 32);
      const float4 b = *(const float4*)(wrow + kk * 32 + 4);
      union { unsigned short s[8]; short8 v; } u;
      u.s[0] = f2bf(a.x); u.s[1] = f2bf(a.y); u.s[2] = f2bf(a.z); u.s[3] = f2bf(a.w);
      u.s[4] = f2bf(b.x); u.s[5] = f2bf(b.y); u.s[6] = f2bf(b.z); u.s[7] = f2bf(b.w);
      aw[kk] = u.v;
    }
  }
  const floatx4 bias4 = *(const floatx4*)(bhid + n0);

  const ull MASKT = 0x8000800080008000ull;
  float v[4] = {0.f, 0.f, 0.f, 0.f};
  const float OMA = 0.9f, AL = 0.1f;

  for (int t = 0; t < SEQ; ++t) {
    // Prefetch u_t: contiguous float4 (hid is the per-lane inner dim now).
    const floatx4 uu = *(const floatx4*)(uo + ((size_t)t * BATCH + b0 + m) * HID + n0);

    floatx4 acc[4];
    #pragma unroll
    for (int j = 0; j < 4; ++j) acc[j] = (floatx4){0.f, 0.f, 0.f, 0.f};

    if (t > 0) {
      const int slot = (t - 1) & 1;
      const ull expv = (((t - 1) >> 1) & 1) ? MASKT : 0ull;
      const ull* ap = frA + (size_t)(slot * BGN + bg) * HG * 128
                          + (size_t)(2 * q) * 16 + m;
      ull lo[HG], hi[HG];
      for (;;) {
        int ok = 1;
        #pragma unroll
        for (int kk = 0; kk < HG; ++kk) {
          lo[kk] = __hip_atomic_load(ap + (size_t)kk * 128,
                                     __ATOMIC_RELAXED, __HIP_MEMORY_SCOPE_AGENT);
          hi[kk] = __hip_atomic_load(ap + (size_t)kk * 128 + 16,
                                     __ATOMIC_RELAXED, __HIP_MEMORY_SCOPE_AGENT);
          ok &= (int)(((lo[kk] & MASKT) == expv) & ((hi[kk] & MASKT) == expv));
        }
        if (__all(ok)) break;
      }
      #pragma unroll
      for (int kk = 0; kk < HG; ++kk) {
        union { ull u[2]; short8 s; } bf;
        bf.u[0] = lo[kk] & ~MASKT;
        bf.u[1] = hi[kk] & ~MASKT;
        acc[kk & 3] = __builtin_amdgcn_mfma_f32_16x16x32_bf16(aw[kk], bf.s,
                                                              acc[kk & 3], 0, 0, 0);
      }
    }

    float fr[4];
    #pragma unroll
    for (int r = 0; r < 4; ++r) {
      float s = acc[0][r] + acc[1][r] + acc[2][r] + acc[3][r];
      v[r] = OMA * v[r] + AL * (s + bias4[r] + uu[r]);
      fr[r] = fmaxf(v[r], 0.f);
    }

    // ---- publish fr_t straight from registers, tagged, fire-and-forget ----
    {
      ull pk = pack4(f2bf(fr[0]), f2bf(fr[1]), f2bf(fr[2]), f2bf(fr[3]));
      if ((t >> 1) & 1) pk |= MASKT;          // step-parity tag in sign bits
      ull* dst = frA + (size_t)(((t & 1) * BGN + bg) * HG + hg) * 128
                     + (size_t)(w * 4 + q) * 16 + m;
      __hip_atomic_store(dst, pk, __ATOMIC_RELAXED, __HIP_MEMORY_SCOPE_AGENT);
    }

    // fp32 output (off critical path): contiguous float4 per lane.
    *(floatx4*)(uo + ((size_t)t * BATCH + b0 + m) * HID + n0) =
        (floatx4){fr[0], fr[1], fr[2], fr[3]};
  }
}

// ---------------------------------------------------------------------------
extern "C" void kernel_launch(void* const* d_in, const int* in_sizes, int n_in,
                              void* d_out, int out_size, void* d_ws, size_t ws_size,
                              hipStream_t stream) {
  const float* inp  = (const float*)d_in[0];
  const float* Win  = (const float*)d_in[1];
  const float* bin  = (const float*)d_in[2];
  const float* Whid = (const float*)d_in[3];
  const float* bhid = (const float*)d_in[4];
  float* out = (float*)d_out;

  ull* frA = (ull*)d_ws;   // 128 KB; 0xAA poison reads as tag=1 => invalid early

  uproj_kernel<<<dim3((65536 / TA_SB) * (HID / TA_H)), dim3(256), 0, stream>>>(
      inp, Win, bin, out);
  scan_kernel<<<dim3(BGN * HG * 2), dim3(64), 0, stream>>>(
      Whid, bhid, out, frA);
}